// Round 1
// baseline (1024.109 us; speedup 1.0000x reference)
//
#include <hip/hip_runtime.h>
#include <math.h>

#define KK 8
#define H 250          // SIZE == h1
#define MDIM 576
#define NB 2048
#define HA 100
#define ROWS (NB*KK)   // 16384
#define PQS 512        // row stride for [P|Q] scratch
#define KTOT 1076      // 250 + 250 + 576
#define EPS 1e-5f

__device__ __forceinline__ void wave_reduce2(float& a, float& b) {
#pragma unroll
    for (int m = 1; m < 64; m <<= 1) {
        a += __shfl_xor(a, m, 64);
        b += __shfl_xor(b, m, 64);
    }
}
__device__ __forceinline__ float wave_reduce1(float a) {
#pragma unroll
    for (int m = 1; m < 64; m <<= 1) a += __shfl_xor(a, m, 64);
    return a;
}

// s1 = LN(relu(state @ enc_W + enc_b))   (16384 x 250)
__global__ __launch_bounds__(256) void k_enc(const float* __restrict__ state,
    const float* __restrict__ W, const float* __restrict__ bias,
    const float* __restrict__ gam, const float* __restrict__ bet,
    float* __restrict__ s1)
{
    __shared__ __align__(16) float st[4][H][8];   // [wave][k][row]
    const int wave = threadIdx.x >> 6, lane = threadIdx.x & 63;
    const int row0 = (blockIdx.x * 4 + wave) * 8;

#pragma unroll
    for (int r = 0; r < 8; ++r)
        for (int kk = lane; kk < H; kk += 64)
            st[wave][kk][r] = state[(size_t)(row0 + r) * H + kk];
    __syncthreads();

    int c[4]; bool val[4]; const float* pW[4];
#pragma unroll
    for (int u = 0; u < 4; ++u) {
        c[u] = lane + 64 * u; val[u] = c[u] < H;
        pW[u] = W + (val[u] ? c[u] : 0);
    }
    float acc[8][4] = {};
    for (int kk = 0; kk < H; ++kk) {
        const float4 sA = *(const float4*)&st[wave][kk][0];
        const float4 sB = *(const float4*)&st[wave][kk][4];
        const float s[8] = {sA.x,sA.y,sA.z,sA.w,sB.x,sB.y,sB.z,sB.w};
        float w[4];
#pragma unroll
        for (int u = 0; u < 4; ++u) { w[u] = *pW[u]; pW[u] += H; }
#pragma unroll
        for (int u = 0; u < 4; ++u)
#pragma unroll
            for (int r = 0; r < 8; ++r)
                acc[r][u] = fmaf(s[r], w[u], acc[r][u]);
    }

    float bv[4], gv[4], btv[4];
#pragma unroll
    for (int u = 0; u < 4; ++u) {
        bv[u]  = val[u] ? bias[c[u]] : 0.f;
        gv[u]  = val[u] ? gam[c[u]]  : 0.f;
        btv[u] = val[u] ? bet[c[u]]  : 0.f;
    }
#pragma unroll
    for (int r = 0; r < 8; ++r) {
        float y[4]; float sm = 0.f, sq = 0.f;
#pragma unroll
        for (int u = 0; u < 4; ++u) {
            float z = val[u] ? fmaxf(acc[r][u] + bv[u], 0.f) : 0.f;
            y[u] = z; sm += z; sq += z * z;
        }
        wave_reduce2(sm, sq);
        const float mu = sm * (1.f / H);
        const float rs = rsqrtf(sq * (1.f / H) - mu * mu + EPS);
#pragma unroll
        for (int u = 0; u < 4; ++u) if (val[u])
            s1[(size_t)(row0 + r) * H + c[u]] = (y[u] - mu) * rs * gv[u] + btv[u];
    }
}

// PQ[row][0:250] = s1 @ core_W[0:250,:] ; PQ[row][250:500] = s1 @ core_W[250:500,:]
__global__ __launch_bounds__(256) void k_pq(const float* __restrict__ s1,
    const float* __restrict__ coreW, float* __restrict__ PQ)
{
    __shared__ __align__(16) float st[4][H][8];
    const int wave = threadIdx.x >> 6, lane = threadIdx.x & 63;
    const int row0 = (blockIdx.x * 4 + wave) * 8;
#pragma unroll
    for (int r = 0; r < 8; ++r)
        for (int kk = lane; kk < H; kk += 64)
            st[wave][kk][r] = s1[(size_t)(row0 + r) * H + kk];
    __syncthreads();

    int c[8]; bool val[8]; const float* pW[8];
#pragma unroll
    for (int u = 0; u < 8; ++u) {
        c[u] = lane + 64 * u; val[u] = c[u] < 2 * H;
        const int off = (c[u] < H) ? c[u] : (H * H + c[u] - H);  // W_bot starts at 250*250
        pW[u] = coreW + (val[u] ? off : 0);
    }
    float acc[8][8] = {};
    for (int kk = 0; kk < H; ++kk) {
        const float4 sA = *(const float4*)&st[wave][kk][0];
        const float4 sB = *(const float4*)&st[wave][kk][4];
        const float s[8] = {sA.x,sA.y,sA.z,sA.w,sB.x,sB.y,sB.z,sB.w};
#pragma unroll
        for (int u = 0; u < 8; ++u) {
            const float w = *pW[u]; pW[u] += H;
#pragma unroll
            for (int r = 0; r < 8; ++r)
                acc[r][u] = fmaf(s[r], w, acc[r][u]);
        }
    }
#pragma unroll
    for (int r = 0; r < 8; ++r)
#pragma unroll
        for (int u = 0; u < 8; ++u) if (val[u])
            PQ[(size_t)(row0 + r) * PQS + c[u]] = acc[r][u];
}

// One wave per (b,i) group: build 7 core_out rows (LN(relu(P+Q+b))), then fused
// [ctx_W | att_W1] GEMM + both LNs + sigmoid gate + weighted sum over the 7 partners.
__global__ __launch_bounds__(256) void k_pairs(
    const float* __restrict__ PQ,
    const float* __restrict__ core_b, const float* __restrict__ core_g, const float* __restrict__ core_bt,
    const float* __restrict__ ctxW, const float* __restrict__ ctx_b, const float* __restrict__ ctx_g, const float* __restrict__ ctx_bt,
    const float* __restrict__ attW1, const float* __restrict__ att_b1, const float* __restrict__ att_g, const float* __restrict__ att_bt,
    const float* __restrict__ attW2, const float* __restrict__ att_b2,
    float* __restrict__ eff)
{
    __shared__ __align__(16) float co[4][H][8];   // [wave][k][pair-row], row 7 = pad
    const int wave = threadIdx.x >> 6, lane = threadIdx.x & 63;
    const int g = blockIdx.x * 4 + wave;          // 0..16383  (= b*8 + i)
    const int i = g & 7;
    const int gbase = g - i;

    int c4[4]; bool v4[4];
#pragma unroll
    for (int u = 0; u < 4; ++u) { c4[u] = lane + 64 * u; v4[u] = c4[u] < H; }

    float Pv[4], cb[4], cg[4], cbt[4];
#pragma unroll
    for (int u = 0; u < 4; ++u) {
        Pv[u]  = v4[u] ? PQ[(size_t)g * PQS + c4[u]] : 0.f;
        cb[u]  = v4[u] ? core_b[c4[u]]  : 0.f;
        cg[u]  = v4[u] ? core_g[c4[u]]  : 0.f;
        cbt[u] = v4[u] ? core_bt[c4[u]] : 0.f;
    }
#pragma unroll
    for (int jj = 0; jj < 7; ++jj) {
        const int j = jj + (jj >= i ? 1 : 0);
        const float* qrow = PQ + (size_t)(gbase + j) * PQS + H;
        float y[4]; float sm = 0.f, sq = 0.f;
#pragma unroll
        for (int u = 0; u < 4; ++u) {
            float z = v4[u] ? fmaxf(Pv[u] + qrow[c4[u]] + cb[u], 0.f) : 0.f;
            y[u] = z; sm += z; sq += z * z;
        }
        wave_reduce2(sm, sq);
        const float mu = sm * (1.f / H);
        const float rs = rsqrtf(sq * (1.f / H) - mu * mu + EPS);
#pragma unroll
        for (int u = 0; u < 4; ++u) if (v4[u])
            co[wave][c4[u]][jj] = (y[u] - mu) * rs * cg[u] + cbt[u];
    }
    __syncthreads();

    // fused GEMM over 350 cols: [0,250) = ctx_W, [250,350) = att_W1
    int c6[6]; const float* pW[6]; int str[6]; bool isC[6], isA[6];
#pragma unroll
    for (int u = 0; u < 6; ++u) {
        c6[u] = lane + 64 * u;
        isC[u] = c6[u] < H;
        isA[u] = (c6[u] >= H) && (c6[u] < H + HA);
        if (isC[u])      { pW[u] = ctxW + c6[u];        str[u] = H;  }
        else if (isA[u]) { pW[u] = attW1 + (c6[u] - H); str[u] = HA; }
        else             { pW[u] = ctxW;                str[u] = 0;  }
    }
    float acc[7][6] = {};
    for (int kk = 0; kk < H; ++kk) {
        const float4 sA = *(const float4*)&co[wave][kk][0];
        const float4 sB = *(const float4*)&co[wave][kk][4];
        const float s[7] = {sA.x,sA.y,sA.z,sA.w,sB.x,sB.y,sB.z};
        float w[6];
#pragma unroll
        for (int u = 0; u < 6; ++u) { w[u] = *pW[u]; pW[u] += str[u]; }
#pragma unroll
        for (int u = 0; u < 6; ++u)
#pragma unroll
            for (int r = 0; r < 7; ++r)
                acc[r][u] = fmaf(s[r], w[u], acc[r][u]);
    }

    float xb[6], xg[6], xbt[6], w2[6];
#pragma unroll
    for (int u = 0; u < 6; ++u) {
        if (isC[u])      { xb[u] = ctx_b[c6[u]]; xg[u] = ctx_g[c6[u]]; xbt[u] = ctx_bt[c6[u]]; w2[u] = 0.f; }
        else if (isA[u]) { const int ca = c6[u] - H;
                           xb[u] = att_b1[ca]; xg[u] = att_g[ca]; xbt[u] = att_bt[ca]; w2[u] = attW2[ca]; }
        else             { xb[u] = xg[u] = xbt[u] = w2[u] = 0.f; }
    }
    const float ab2 = att_b2[0];
    float effa[4] = {0.f, 0.f, 0.f, 0.f};

#pragma unroll
    for (int r = 0; r < 7; ++r) {
        float zc[4]; float smc = 0.f, sqc = 0.f;
#pragma unroll
        for (int u = 0; u < 4; ++u) {
            float z = isC[u] ? fmaxf(acc[r][u] + xb[u], 0.f) : 0.f;
            zc[u] = z; smc += z; sqc += z * z;
        }
        float za[6]; float sma = 0.f, sqa = 0.f;
#pragma unroll
        for (int u = 3; u < 6; ++u) {
            float z = isA[u] ? tanhf(acc[r][u] + xb[u]) : 0.f;
            za[u] = z; sma += z; sqa += z * z;
        }
        wave_reduce2(smc, sqc);
        wave_reduce2(sma, sqa);
        const float muC = smc * (1.f / H);
        const float rsC = rsqrtf(sqc * (1.f / H) - muC * muC + EPS);
        const float muA = sma * (1.f / HA);
        const float rsA = rsqrtf(sqa * (1.f / HA) - muA * muA + EPS);
        float dot = 0.f;
#pragma unroll
        for (int u = 3; u < 6; ++u) if (isA[u]) {
            const float ath = (za[u] - muA) * rsA * xg[u] + xbt[u];
            dot += ath * w2[u];
        }
        dot = wave_reduce1(dot);
        const float a = 1.f / (1.f + expf(-(dot + ab2)));
#pragma unroll
        for (int u = 0; u < 4; ++u) if (isC[u]) {
            const float ctxo = (zc[u] - muC) * rsC * xg[u] + xbt[u];
            effa[u] = fmaf(a, ctxo, effa[u]);
        }
    }
#pragma unroll
    for (int u = 0; u < 4; ++u) if (v4[u])
        eff[(size_t)g * H + c4[u]] = effa[u];
}

// new_state = [s1 | eff | x] @ out_W + out_b, K streamed in 128-chunks through LDS
__global__ __launch_bounds__(256) void k_out(
    const float* __restrict__ s1, const float* __restrict__ eff,
    const float* __restrict__ x, const float* __restrict__ Wo,
    const float* __restrict__ ob, float* __restrict__ out)
{
    __shared__ __align__(16) float at[4][128][8];
    const int wave = threadIdx.x >> 6, lane = threadIdx.x & 63;
    const int row0 = (blockIdx.x * 4 + wave) * 8;
    int c[4]; bool val[4]; const float* pW[4];
#pragma unroll
    for (int u = 0; u < 4; ++u) {
        c[u] = lane + 64 * u; val[u] = c[u] < H;
        pW[u] = Wo + (val[u] ? c[u] : 0);
    }
    float acc[8][4] = {};
    for (int k0 = 0; k0 < KTOT; k0 += 128) {
        const int kc = min(128, KTOT - k0);
        __syncthreads();
#pragma unroll
        for (int r = 0; r < 8; ++r) {
            for (int t = lane; t < kc; t += 64) {
                const int kk = k0 + t;
                float v;
                if (kk < H)          v = s1[(size_t)(row0 + r) * H + kk];
                else if (kk < 2 * H) v = eff[(size_t)(row0 + r) * H + (kk - H)];
                else                 v = x[(size_t)(row0 + r) * MDIM + (kk - 2 * H)];
                at[wave][t][r] = v;
            }
        }
        __syncthreads();
#pragma unroll 4
        for (int t = 0; t < kc; ++t) {
            const float4 sA = *(const float4*)&at[wave][t][0];
            const float4 sB = *(const float4*)&at[wave][t][4];
            const float s[8] = {sA.x,sA.y,sA.z,sA.w,sB.x,sB.y,sB.z,sB.w};
            float w[4];
#pragma unroll
            for (int u = 0; u < 4; ++u) { w[u] = *pW[u]; pW[u] += H; }
#pragma unroll
            for (int u = 0; u < 4; ++u)
#pragma unroll
                for (int r = 0; r < 8; ++r)
                    acc[r][u] = fmaf(s[r], w[u], acc[r][u]);
        }
    }
    float obv[4];
#pragma unroll
    for (int u = 0; u < 4; ++u) obv[u] = val[u] ? ob[c[u]] : 0.f;
#pragma unroll
    for (int r = 0; r < 8; ++r)
#pragma unroll
        for (int u = 0; u < 4; ++u) if (val[u])
            out[(size_t)(row0 + r) * H + c[u]] = acc[r][u] + obv[u];
}

extern "C" void kernel_launch(void* const* d_in, const int* in_sizes, int n_in,
                              void* d_out, int out_size, void* d_ws, size_t ws_size,
                              hipStream_t stream)
{
    const float* x      = (const float*)d_in[0];
    const float* state  = (const float*)d_in[1];
    const float* enc_W  = (const float*)d_in[2];
    const float* enc_b  = (const float*)d_in[3];
    const float* enc_g  = (const float*)d_in[4];
    const float* enc_bt = (const float*)d_in[5];
    const float* core_W = (const float*)d_in[6];
    const float* core_b = (const float*)d_in[7];
    const float* core_g = (const float*)d_in[8];
    const float* core_bt= (const float*)d_in[9];
    const float* ctx_W  = (const float*)d_in[10];
    const float* ctx_b  = (const float*)d_in[11];
    const float* ctx_g  = (const float*)d_in[12];
    const float* ctx_bt = (const float*)d_in[13];
    const float* att_W1 = (const float*)d_in[14];
    const float* att_b1 = (const float*)d_in[15];
    const float* att_g  = (const float*)d_in[16];
    const float* att_bt = (const float*)d_in[17];
    const float* att_W2 = (const float*)d_in[18];
    const float* att_b2 = (const float*)d_in[19];
    const float* out_W  = (const float*)d_in[20];
    const float* out_b  = (const float*)d_in[21];
    float* out = (float*)d_out;

    float* s1  = (float*)d_ws;                 // 16384*250
    float* PQ  = s1 + (size_t)ROWS * H;        // 16384*512
    float* eff = PQ + (size_t)ROWS * PQS;      // 16384*250

    k_enc<<<ROWS / 32, 256, 0, stream>>>(state, enc_W, enc_b, enc_g, enc_bt, s1);
    k_pq<<<ROWS / 32, 256, 0, stream>>>(s1, core_W, PQ);
    k_pairs<<<ROWS / 4, 256, 0, stream>>>(PQ, core_b, core_g, core_bt,
        ctx_W, ctx_b, ctx_g, ctx_bt, att_W1, att_b1, att_g, att_bt,
        att_W2, att_b2, eff);
    k_out<<<ROWS / 32, 256, 0, stream>>>(s1, eff, x, out_W, out_b, out);
}

// Round 2
// 673.462 us; speedup vs baseline: 1.5207x; 1.5207x over previous
//
#include <hip/hip_runtime.h>
#include <hip/hip_bf16.h>
#include <math.h>

#define KK 8
#define H 250          // SIZE == h1
#define MDIM 576
#define NB 2048
#define HA 100
#define ROWS (NB*KK)   // 16384
#define PQS 512        // row stride for [P|Q] scratch
#define KP 1088        // padded K for out GEMM (1076 -> 34*32)
#define NP 256         // padded N for out GEMM
#define EPS 1e-5f

typedef unsigned short ushort_t;
typedef short short8 __attribute__((ext_vector_type(8)));
typedef float f32x4 __attribute__((ext_vector_type(4)));

__device__ __forceinline__ void wave_reduce2(float& a, float& b) {
#pragma unroll
    for (int m = 1; m < 64; m <<= 1) {
        a += __shfl_xor(a, m, 64);
        b += __shfl_xor(b, m, 64);
    }
}
__device__ __forceinline__ float wave_reduce1(float a) {
#pragma unroll
    for (int m = 1; m < 64; m <<= 1) a += __shfl_xor(a, m, 64);
    return a;
}

__device__ __forceinline__ void async_copy16(const void* g, void* l) {
    __builtin_amdgcn_global_load_lds(
        (const __attribute__((address_space(1))) void*)g,
        (__attribute__((address_space(3))) void*)l, 16, 0, 0);
}

__device__ __forceinline__ ushort_t f2bf(float v) {
    union { float f; unsigned int u; } c; c.f = v;
    unsigned int x = c.u;
    x += 0x7fff + ((x >> 16) & 1);   // RNE
    return (ushort_t)(x >> 16);
}

// s1 = LN(relu(state @ enc_W + enc_b))   (16384 x 250), fp32 + bf16 copies
__global__ __launch_bounds__(256) void k_enc(const float* __restrict__ state,
    const float* __restrict__ W, const float* __restrict__ bias,
    const float* __restrict__ gam, const float* __restrict__ bet,
    float* __restrict__ s1, ushort_t* __restrict__ Abuf)
{
    __shared__ __align__(16) float st[4][H][8];   // [wave][k][row]
    const int wave = threadIdx.x >> 6, lane = threadIdx.x & 63;
    const int row0 = (blockIdx.x * 4 + wave) * 8;

#pragma unroll
    for (int r = 0; r < 8; ++r)
        for (int kk = lane; kk < H; kk += 64)
            st[wave][kk][r] = state[(size_t)(row0 + r) * H + kk];
    __syncthreads();

    int c[4]; bool val[4]; const float* pW[4];
#pragma unroll
    for (int u = 0; u < 4; ++u) {
        c[u] = lane + 64 * u; val[u] = c[u] < H;
        pW[u] = W + (val[u] ? c[u] : 0);
    }
    float acc[8][4] = {};
    for (int kk = 0; kk < H; ++kk) {
        const float4 sA = *(const float4*)&st[wave][kk][0];
        const float4 sB = *(const float4*)&st[wave][kk][4];
        const float s[8] = {sA.x,sA.y,sA.z,sA.w,sB.x,sB.y,sB.z,sB.w};
        float w[4];
#pragma unroll
        for (int u = 0; u < 4; ++u) { w[u] = *pW[u]; pW[u] += H; }
#pragma unroll
        for (int u = 0; u < 4; ++u)
#pragma unroll
            for (int r = 0; r < 8; ++r)
                acc[r][u] = fmaf(s[r], w[u], acc[r][u]);
    }

    float bv[4], gv[4], btv[4];
#pragma unroll
    for (int u = 0; u < 4; ++u) {
        bv[u]  = val[u] ? bias[c[u]] : 0.f;
        gv[u]  = val[u] ? gam[c[u]]  : 0.f;
        btv[u] = val[u] ? bet[c[u]]  : 0.f;
    }
#pragma unroll
    for (int r = 0; r < 8; ++r) {
        float y[4]; float sm = 0.f, sq = 0.f;
#pragma unroll
        for (int u = 0; u < 4; ++u) {
            float z = val[u] ? fmaxf(acc[r][u] + bv[u], 0.f) : 0.f;
            y[u] = z; sm += z; sq += z * z;
        }
        wave_reduce2(sm, sq);
        const float mu = sm * (1.f / H);
        const float rs = rsqrtf(sq * (1.f / H) - mu * mu + EPS);
#pragma unroll
        for (int u = 0; u < 4; ++u) if (val[u]) {
            const float o = (y[u] - mu) * rs * gv[u] + btv[u];
            s1[(size_t)(row0 + r) * H + c[u]] = o;
            Abuf[(size_t)(row0 + r) * KP + c[u]] = f2bf(o);
        }
    }
}

// PQ[row][0:250] = s1 @ core_W[0:250,:] ; PQ[row][250:500] = s1 @ core_W[250:500,:]
__global__ __launch_bounds__(256) void k_pq(const float* __restrict__ s1,
    const float* __restrict__ coreW, float* __restrict__ PQ)
{
    __shared__ __align__(16) float st[4][H][8];
    const int wave = threadIdx.x >> 6, lane = threadIdx.x & 63;
    const int row0 = (blockIdx.x * 4 + wave) * 8;
#pragma unroll
    for (int r = 0; r < 8; ++r)
        for (int kk = lane; kk < H; kk += 64)
            st[wave][kk][r] = s1[(size_t)(row0 + r) * H + kk];
    __syncthreads();

    int c[8]; bool val[8]; const float* pW[8];
#pragma unroll
    for (int u = 0; u < 8; ++u) {
        c[u] = lane + 64 * u; val[u] = c[u] < 2 * H;
        const int off = (c[u] < H) ? c[u] : (H * H + c[u] - H);
        pW[u] = coreW + (val[u] ? off : 0);
    }
    float acc[8][8] = {};
    for (int kk = 0; kk < H; ++kk) {
        const float4 sA = *(const float4*)&st[wave][kk][0];
        const float4 sB = *(const float4*)&st[wave][kk][4];
        const float s[8] = {sA.x,sA.y,sA.z,sA.w,sB.x,sB.y,sB.z,sB.w};
#pragma unroll
        for (int u = 0; u < 8; ++u) {
            const float w = *pW[u]; pW[u] += H;
#pragma unroll
            for (int r = 0; r < 8; ++r)
                acc[r][u] = fmaf(s[r], w, acc[r][u]);
        }
    }
#pragma unroll
    for (int r = 0; r < 8; ++r)
#pragma unroll
        for (int u = 0; u < 8; ++u) if (val[u])
            PQ[(size_t)(row0 + r) * PQS + c[u]] = acc[r][u];
}

// One wave per (b,i) group; writes eff (bf16) straight into Abuf cols [250,500)
__global__ __launch_bounds__(256) void k_pairs(
    const float* __restrict__ PQ,
    const float* __restrict__ core_b, const float* __restrict__ core_g, const float* __restrict__ core_bt,
    const float* __restrict__ ctxW, const float* __restrict__ ctx_b, const float* __restrict__ ctx_g, const float* __restrict__ ctx_bt,
    const float* __restrict__ attW1, const float* __restrict__ att_b1, const float* __restrict__ att_g, const float* __restrict__ att_bt,
    const float* __restrict__ attW2, const float* __restrict__ att_b2,
    ushort_t* __restrict__ Abuf)
{
    __shared__ __align__(16) float co[4][H][8];   // [wave][k][pair-row]
    const int wave = threadIdx.x >> 6, lane = threadIdx.x & 63;
    const int g = blockIdx.x * 4 + wave;          // 0..16383  (= b*8 + i)
    const int i = g & 7;
    const int gbase = g - i;

    int c4[4]; bool v4[4];
#pragma unroll
    for (int u = 0; u < 4; ++u) { c4[u] = lane + 64 * u; v4[u] = c4[u] < H; }

    float Pv[4], cb[4], cg[4], cbt[4];
#pragma unroll
    for (int u = 0; u < 4; ++u) {
        Pv[u]  = v4[u] ? PQ[(size_t)g * PQS + c4[u]] : 0.f;
        cb[u]  = v4[u] ? core_b[c4[u]]  : 0.f;
        cg[u]  = v4[u] ? core_g[c4[u]]  : 0.f;
        cbt[u] = v4[u] ? core_bt[c4[u]] : 0.f;
    }
#pragma unroll
    for (int jj = 0; jj < 7; ++jj) {
        const int j = jj + (jj >= i ? 1 : 0);
        const float* qrow = PQ + (size_t)(gbase + j) * PQS + H;
        float y[4]; float sm = 0.f, sq = 0.f;
#pragma unroll
        for (int u = 0; u < 4; ++u) {
            float z = v4[u] ? fmaxf(Pv[u] + qrow[c4[u]] + cb[u], 0.f) : 0.f;
            y[u] = z; sm += z; sq += z * z;
        }
        wave_reduce2(sm, sq);
        const float mu = sm * (1.f / H);
        const float rs = rsqrtf(sq * (1.f / H) - mu * mu + EPS);
#pragma unroll
        for (int u = 0; u < 4; ++u) if (v4[u])
            co[wave][c4[u]][jj] = (y[u] - mu) * rs * cg[u] + cbt[u];
    }
    __syncthreads();

    int c6[6]; const float* pW[6]; int str[6]; bool isC[6], isA[6];
#pragma unroll
    for (int u = 0; u < 6; ++u) {
        c6[u] = lane + 64 * u;
        isC[u] = c6[u] < H;
        isA[u] = (c6[u] >= H) && (c6[u] < H + HA);
        if (isC[u])      { pW[u] = ctxW + c6[u];        str[u] = H;  }
        else if (isA[u]) { pW[u] = attW1 + (c6[u] - H); str[u] = HA; }
        else             { pW[u] = ctxW;                str[u] = 0;  }
    }
    float acc[7][6] = {};
    for (int kk = 0; kk < H; ++kk) {
        const float4 sA = *(const float4*)&co[wave][kk][0];
        const float4 sB = *(const float4*)&co[wave][kk][4];
        const float s[7] = {sA.x,sA.y,sA.z,sA.w,sB.x,sB.y,sB.z};
        float w[6];
#pragma unroll
        for (int u = 0; u < 6; ++u) { w[u] = *pW[u]; pW[u] += str[u]; }
#pragma unroll
        for (int u = 0; u < 6; ++u)
#pragma unroll
            for (int r = 0; r < 7; ++r)
                acc[r][u] = fmaf(s[r], w[u], acc[r][u]);
    }

    float xb[6], xg[6], xbt[6], w2[6];
#pragma unroll
    for (int u = 0; u < 6; ++u) {
        if (isC[u])      { xb[u] = ctx_b[c6[u]]; xg[u] = ctx_g[c6[u]]; xbt[u] = ctx_bt[c6[u]]; w2[u] = 0.f; }
        else if (isA[u]) { const int ca = c6[u] - H;
                           xb[u] = att_b1[ca]; xg[u] = att_g[ca]; xbt[u] = att_bt[ca]; w2[u] = attW2[ca]; }
        else             { xb[u] = xg[u] = xbt[u] = w2[u] = 0.f; }
    }
    const float ab2 = att_b2[0];
    float effa[4] = {0.f, 0.f, 0.f, 0.f};

#pragma unroll
    for (int r = 0; r < 7; ++r) {
        float zc[4]; float smc = 0.f, sqc = 0.f;
#pragma unroll
        for (int u = 0; u < 4; ++u) {
            float z = isC[u] ? fmaxf(acc[r][u] + xb[u], 0.f) : 0.f;
            zc[u] = z; smc += z; sqc += z * z;
        }
        float za[6]; float sma = 0.f, sqa = 0.f;
#pragma unroll
        for (int u = 3; u < 6; ++u) {
            float z = isA[u] ? tanhf(acc[r][u] + xb[u]) : 0.f;
            za[u] = z; sma += z; sqa += z * z;
        }
        wave_reduce2(smc, sqc);
        wave_reduce2(sma, sqa);
        const float muC = smc * (1.f / H);
        const float rsC = rsqrtf(sqc * (1.f / H) - muC * muC + EPS);
        const float muA = sma * (1.f / HA);
        const float rsA = rsqrtf(sqa * (1.f / HA) - muA * muA + EPS);
        float dot = 0.f;
#pragma unroll
        for (int u = 3; u < 6; ++u) if (isA[u]) {
            const float ath = (za[u] - muA) * rsA * xg[u] + xbt[u];
            dot += ath * w2[u];
        }
        dot = wave_reduce1(dot);
        const float a = 1.f / (1.f + expf(-(dot + ab2)));
#pragma unroll
        for (int u = 0; u < 4; ++u) if (isC[u]) {
            const float ctxo = (zc[u] - muC) * rsC * xg[u] + xbt[u];
            effa[u] = fmaf(a, ctxo, effa[u]);
        }
    }
#pragma unroll
    for (int u = 0; u < 4; ++u) if (v4[u])
        Abuf[(size_t)g * KP + H + c4[u]] = f2bf(effa[u]);
}

// Abuf cols [500,1088): x (bf16) + zero pad. One block per row.
__global__ __launch_bounds__(256) void k_prepx(const float* __restrict__ x,
                                               ushort_t* __restrict__ Abuf)
{
    const int row = blockIdx.x;
    for (int c = 500 + threadIdx.x; c < KP; c += 256) {
        const float v = (c < 500 + MDIM) ? x[(size_t)row * MDIM + (c - 500)] : 0.f;
        Abuf[(size_t)row * KP + c] = f2bf(v);
    }
}

// Wt[n][k] = out_W[k][n], padded to 256 x 1088, bf16
__global__ __launch_bounds__(256) void k_prepw(const float* __restrict__ Wo,
                                               ushort_t* __restrict__ Wt)
{
    const int n = blockIdx.x;   // 0..255
    for (int k = threadIdx.x; k < KP; k += 256) {
        const float v = (n < H && k < 1076) ? Wo[(size_t)k * H + n] : 0.f;
        Wt[(size_t)n * KP + k] = f2bf(v);
    }
}

// C[16384 x 250] = A[16384 x 1088] @ Wt^T + out_b   (bf16 MFMA, fp32 acc)
// 64x64 tiles, BK=32, 4 waves (2x2), each wave 32x32 via 2x2 of 16x16x32 MFMA.
__global__ __launch_bounds__(256) void k_gemm_out(
    const ushort_t* __restrict__ A, const ushort_t* __restrict__ Bt,
    const float* __restrict__ bias, float* __restrict__ C)
{
    __shared__ __align__(16) ushort_t As[64 * 32];
    __shared__ __align__(16) ushort_t Bs[64 * 32];
    const int tid  = threadIdx.x;
    const int lane = tid & 63, wave = tid >> 6;
    const int wm = wave >> 1, wn = wave & 1;
    const int mtile = (int)blockIdx.x >> 2, ntile = (int)blockIdx.x & 3;
    const int m0 = mtile * 64, n0 = ntile * 64;

    // staging: thread tid copies one 16B chunk of A and one of B per k-step.
    // LDS chunk position = srow*4 + cs holds logical chunk cs ^ ((srow>>1)&3)
    // (XOR swizzle -> 2-way max bank aliasing on ds_read_b128, free per m136)
    const int srow = tid >> 2;
    const int cs   = tid & 3;
    const int cl   = cs ^ ((srow >> 1) & 3);
    const ushort_t* gA = A  + (size_t)(m0 + srow) * KP + cl * 8;
    const ushort_t* gB = Bt + (size_t)(n0 + srow) * KP + cl * 8;
    ushort_t* lA = &As[tid * 8];
    ushort_t* lB = &Bs[tid * 8];

    const int q  = lane >> 4;      // quad: k-offset q*8
    const int fr = lane & 15;      // row/col within 16x16 tile
    int aoff[2], boff[2];
#pragma unroll
    for (int s = 0; s < 2; ++s) {
        const int ra = wm * 32 + s * 16 + fr;
        aoff[s] = (ra * 4 + (q ^ ((ra >> 1) & 3))) * 8;
        const int rb = wn * 32 + s * 16 + fr;
        boff[s] = (rb * 4 + (q ^ ((rb >> 1) & 3))) * 8;
    }

    f32x4 acc[2][2] = {};
    for (int k0 = 0; k0 < KP; k0 += 32) {
        async_copy16(gA + k0, lA);
        async_copy16(gB + k0, lB);
        __syncthreads();
        short8 a[2], b[2];
#pragma unroll
        for (int s = 0; s < 2; ++s) {
            a[s] = *(const short8*)&As[aoff[s]];
            b[s] = *(const short8*)&Bs[boff[s]];
        }
#pragma unroll
        for (int ms = 0; ms < 2; ++ms)
#pragma unroll
            for (int ns = 0; ns < 2; ++ns)
                acc[ms][ns] = __builtin_amdgcn_mfma_f32_16x16x32_bf16(
                    a[ms], b[ns], acc[ms][ns], 0, 0, 0);
        __syncthreads();
    }

    // C/D layout: col = lane&15, row = (lane>>4)*4 + reg  [m89-verified]
#pragma unroll
    for (int ms = 0; ms < 2; ++ms)
#pragma unroll
        for (int ns = 0; ns < 2; ++ns) {
            const int n_abs = n0 + wn * 32 + ns * 16 + fr;
            if (n_abs >= H) continue;
            const float bv = bias[n_abs];
#pragma unroll
            for (int reg = 0; reg < 4; ++reg) {
                const int m_abs = m0 + wm * 32 + ms * 16 + q * 4 + reg;
                C[(size_t)m_abs * H + n_abs] = acc[ms][ns][reg] + bv;
            }
        }
}

extern "C" void kernel_launch(void* const* d_in, const int* in_sizes, int n_in,
                              void* d_out, int out_size, void* d_ws, size_t ws_size,
                              hipStream_t stream)
{
    const float* x      = (const float*)d_in[0];
    const float* state  = (const float*)d_in[1];
    const float* enc_W  = (const float*)d_in[2];
    const float* enc_b  = (const float*)d_in[3];
    const float* enc_g  = (const float*)d_in[4];
    const float* enc_bt = (const float*)d_in[5];
    const float* core_W = (const float*)d_in[6];
    const float* core_b = (const float*)d_in[7];
    const float* core_g = (const float*)d_in[8];
    const float* core_bt= (const float*)d_in[9];
    const float* ctx_W  = (const float*)d_in[10];
    const float* ctx_b  = (const float*)d_in[11];
    const float* ctx_g  = (const float*)d_in[12];
    const float* ctx_bt = (const float*)d_in[13];
    const float* att_W1 = (const float*)d_in[14];
    const float* att_b1 = (const float*)d_in[15];
    const float* att_g  = (const float*)d_in[16];
    const float* att_bt = (const float*)d_in[17];
    const float* att_W2 = (const float*)d_in[18];
    const float* att_b2 = (const float*)d_in[19];
    const float* out_W  = (const float*)d_in[20];
    const float* out_b  = (const float*)d_in[21];
    float* out = (float*)d_out;

    float* s1  = (float*)d_ws;                         // 16384*250 f32
    float* PQ  = s1 + (size_t)ROWS * H;                // 16384*512 f32
    ushort_t* Abuf = (ushort_t*)(PQ + (size_t)ROWS * PQS);   // 16384*1088 bf16
    ushort_t* Wt   = Abuf + (size_t)ROWS * KP;               // 256*1088 bf16

    k_prepw<<<NP, 256, 0, stream>>>(out_W, Wt);
    k_prepx<<<ROWS, 256, 0, stream>>>(x, Abuf);
    k_enc<<<ROWS / 32, 256, 0, stream>>>(state, enc_W, enc_b, enc_g, enc_bt, s1, Abuf);
    k_pq<<<ROWS / 32, 256, 0, stream>>>(s1, core_W, PQ);
    k_pairs<<<ROWS / 4, 256, 0, stream>>>(PQ, core_b, core_g, core_bt,
        ctx_W, ctx_b, ctx_g, ctx_bt, att_W1, att_b1, att_g, att_bt,
        att_W2, att_b2, Abuf);
    k_gemm_out<<<(ROWS / 64) * (NP / 64), 256, 0, stream>>>(Abuf, Wt, out_b, out);
}